// Round 7
// baseline (281.604 us; speedup 1.0000x reference)
//
#include <hip/hip_runtime.h>
#include <hip/hip_bf16.h>

#define BATCH  4096
#define UNITS  1024
#define CDIM   2048   // K = UNITS + IN_DIM
#define NDIM   4096   // 4 * UNITS (f, i, c, o)

typedef __attribute__((ext_vector_type(8))) short bf16x8;
typedef __attribute__((ext_vector_type(4))) float f32x4;

__device__ __forceinline__ void gload_lds16(const void* g, void* l) {
    __builtin_amdgcn_global_load_lds(
        (const __attribute__((address_space(1))) unsigned int*)g,
        (__attribute__((address_space(3))) unsigned int*)l, 16, 0, 0);
}

__device__ __forceinline__ float sigm(float x) { return 1.f / (1.f + __expf(-x)); }
__device__ __forceinline__ float tanh_fast(float x) { return 2.f / (1.f + __expf(-2.f * x)) - 1.f; }

// ---- prep: concat-cast x + transpose-cast-permute W, fully vectorized -------
// Wt row layout (gate-interleaved, 32-periodic within 128-blocks):
//   n(U,g) = (U>>5)*128 + g*32 + (U&31)
__global__ void prep(const float* __restrict__ h, const float* __restrict__ in,
                     const float* __restrict__ Wf, const float* __restrict__ Wi,
                     const float* __restrict__ Wc, const float* __restrict__ Wo,
                     __hip_bfloat16* __restrict__ x, __hip_bfloat16* __restrict__ Wt) {
    __shared__ float tile[64 * 65];
    int b = blockIdx.x, tid = threadIdx.x;
    if (b < 4096) {
        // concat(hidden, inputs) -> bf16 x [BATCH, CDIM], 8 floats per thread
        int t   = b * 256 + tid;
        int row = t >> 8;
        int c8  = (t & 255) * 8;
        const float* src = (c8 < UNITS) ? (h + (size_t)row * UNITS + c8)
                                        : (in + (size_t)row * UNITS + (c8 - UNITS));
        float4 v0 = *(const float4*)src;
        float4 v1 = *(const float4*)(src + 4);
        union { __hip_bfloat16 b[8]; bf16x8 v; } pk;
        pk.b[0] = __float2bfloat16(v0.x); pk.b[1] = __float2bfloat16(v0.y);
        pk.b[2] = __float2bfloat16(v0.z); pk.b[3] = __float2bfloat16(v0.w);
        pk.b[4] = __float2bfloat16(v1.x); pk.b[5] = __float2bfloat16(v1.y);
        pk.b[6] = __float2bfloat16(v1.z); pk.b[7] = __float2bfloat16(v1.w);
        *(bf16x8*)(x + (size_t)row * CDIM + c8) = pk.v;
    } else {
        // W_g[CDIM, UNITS] f32 -> Wt[n(U,g), k] bf16, 64k x 64u tile
        int idx = b - 4096;                       // 2048 blocks: 4g x 32ky x 16ux
        int g = idx >> 9, rest = idx & 511, ky = rest >> 4, ux = rest & 15;
        const float* W = (g == 0) ? Wf : (g == 1) ? Wi : (g == 2) ? Wc : Wo;
        int k0 = ky * 64, u0 = ux * 64;
#pragma unroll
        for (int q = 0; q < 4; ++q) {
            int s = q * 256 + tid;                // 1024 float4 slots
            int row = s >> 4, c4 = s & 15;
            float4 v = *(const float4*)&W[(size_t)(k0 + row) * UNITS + u0 + c4 * 4];
            *(float4*)&tile[row * 65 + c4 * 4] = v;
        }
        __syncthreads();
#pragma unroll
        for (int q = 0; q < 2; ++q) {
            int s = q * 256 + tid;                // 512 slots
            int u = s >> 3, kc = s & 7;
            int U = u0 + u;
            int n = ((U >> 5) << 7) + (g << 5) + (U & 31);
            union { __hip_bfloat16 b[8]; bf16x8 v; } pk;
#pragma unroll
            for (int j = 0; j < 8; ++j)
                pk.b[j] = __float2bfloat16(tile[(kc * 8 + j) * 65 + u]);
            *(bf16x8*)(Wt + (size_t)n * CDIM + k0 + kc * 8) = pk.v;
        }
    }
}

// ---- barrier-free fused GEMM + LSTM gates (r6 fixed) ------------------------
// Block 256m x 128n, 4 waves; wave = PRIVATE 64m slice x 128n (4i x 8j MFMA).
// Wave-private double-buffered A LDS via global_load_lds; B L2->regs 1-ahead.
// NO s_barrier: DMA->ds_read ordering enforced by per-wave s_waitcnt vmcnt(12)
// (the fine-grained wait a block barrier cannot express). Swizzle g(row)=
// (row>>1)&3 gives 2-way (free) LDS banking. WAR on buffers is safe by
// construction: all MFMAs of compute(p) issue (and their ds_reads complete,
// forced by lgkmcnt) before stage(p)'s DMA issues.
__global__ __launch_bounds__(256, 2) void gemm_lstm(
    const __hip_bfloat16* __restrict__ A,    // [BATCH, CDIM] bf16
    const __hip_bfloat16* __restrict__ Bt,   // [NDIM, CDIM] bf16, gate-interleaved
    const float* __restrict__ b_f, const float* __restrict__ b_i,
    const float* __restrict__ b_c, const float* __restrict__ b_o,
    const float* __restrict__ cell,          // [BATCH, UNITS]
    float* __restrict__ out)                 // [2, BATCH, UNITS]: hidden, cell
{
    __shared__ short As[4][2][64 * 32];      // [wave][buf][64 rows x 32 k], 4 KB
    const int K = CDIM;

    int bid = blockIdx.x;
    int nb  = (bid & 7) * 4 + ((bid >> 3) & 3);   // same-nb blocks share an XCD
    int mb  = bid >> 5;
    int m0  = mb * 256, n0 = nb * 128;

    int tid  = threadIdx.x;
    int w    = tid >> 6, lane = tid & 63;
    int quad = lane >> 4, r16 = lane & 15;

    f32x4 acc[4][8];
#pragma unroll
    for (int i = 0; i < 4; ++i)
#pragma unroll
        for (int j = 0; j < 8; ++j) acc[i][j] = (f32x4){0.f, 0.f, 0.f, 0.f};

    const short* Ag = (const short*)A  + (size_t)(m0 + w * 64) * K;   // wave's rows
    const short* Bg = (const short*)Bt + (size_t)(n0 + r16) * K + quad * 8;

    // stage wave's 64x32 A-slice into private buf p.
    // LDS slot (row, cs) holds global chunk cs ^ ((row>>1)&3)  [2-way banks]
    auto stage = [&](int p, int k0) {
        short* dst = As[w][p];
#pragma unroll
        for (int q = 0; q < 4; ++q) {
            int s   = q * 64 + lane;           // 256 chunks of 16B
            int row = s >> 2;
            int cg  = (s & 3) ^ ((row >> 1) & 3);
            gload_lds16(Ag + (size_t)row * K + k0 + cg * 8, dst + s * 8);
        }
    };
    auto loadB = [&](bf16x8* Bv, int k0) {
#pragma unroll
        for (int j = 0; j < 8; ++j)
            Bv[j] = *(const bf16x8*)&Bg[(size_t)(j * 16) * K + k0];
    };
    auto compute = [&](int p, const bf16x8* Bv) {
        bf16x8 af[4];
#pragma unroll
        for (int i = 0; i < 4; ++i) {
            int row = i * 16 + r16;
            int cs  = quad ^ ((r16 >> 1) & 3);     // == quad ^ ((row>>1)&3)
            af[i] = *(const bf16x8*)&As[w][p][(row * 4 + cs) * 8];
        }
#pragma unroll
        for (int i = 0; i < 4; ++i)
#pragma unroll
            for (int j = 0; j < 8; ++j)
                acc[i][j] = __builtin_amdgcn_mfma_f32_16x16x32_bf16(af[i], Bv[j], acc[i][j], 0, 0, 0);
    };

    bf16x8 B0[8], B1[8];
    stage(0, 0);                               // 4 DMA
    loadB(B0, 0);                              // 8 loads  -> 12 outstanding

    // Steady state: 24 VMEM ops in flight; vmcnt(12) retires exactly the
    // previous phase's 4 DMA + 8 B-loads. Per-wave, self-paced, no barriers.
    for (int kt = 0; kt < K / 32; kt += 2) {
        int k1 = (kt + 1) * 32;
        int k2 = min((kt + 2) * 32, K - 32);   // tail clamp (staged, never read)
        stage(1, k1);
        loadB(B1, k1);
        asm volatile("s_waitcnt vmcnt(12)" ::: "memory");  // buf0 DMA + B0 done
        compute(0, B0);
        asm volatile("" ::: "memory");         // pin: reads precede buf0 overwrite
        stage(0, k2);
        loadB(B0, k2);
        asm volatile("s_waitcnt vmcnt(12)" ::: "memory");  // buf1 DMA + B1 done
        compute(1, B1);
        asm volatile("" ::: "memory");
    }

    // ---- fused LSTM epilogue --------------------------------------------------
    // j-tile j = (gate g = j>>1, u-half uu = j&1); u = nb*32 + uu*16 + r16.
    // C/D layout: col=lane&15, row=quad*4+reg (m89-verified)
    float* out_h = out;
    float* out_c = out + (size_t)BATCH * UNITS;
#pragma unroll
    for (int uu = 0; uu < 2; ++uu) {
        int u = nb * 32 + uu * 16 + r16;
        float bfv = b_f[u], biv = b_i[u], bcv = b_c[u], bov = b_o[u];
#pragma unroll
        for (int i = 0; i < 4; ++i) {
#pragma unroll
            for (int rr = 0; rr < 4; ++rr) {
                int m = m0 + w * 64 + i * 16 + quad * 4 + rr;
                float fg = sigm(acc[i][0 * 2 + uu][rr] + bfv);
                float ig = sigm(acc[i][1 * 2 + uu][rr] + biv);
                float cc = tanh_fast(acc[i][2 * 2 + uu][rr] + bcv);
                float og = sigm(acc[i][3 * 2 + uu][rr] + bov);
                float cold = cell[(size_t)m * UNITS + u];
                float cn = fg * cold + ig * cc;
                out_h[(size_t)m * UNITS + u] = og * tanh_fast(cn);
                out_c[(size_t)m * UNITS + u] = cn;
            }
        }
    }
}

extern "C" void kernel_launch(void* const* d_in, const int* in_sizes, int n_in,
                              void* d_out, int out_size, void* d_ws, size_t ws_size,
                              hipStream_t stream) {
    const float* inputs = (const float*)d_in[0];
    const float* hidden = (const float*)d_in[1];
    const float* cell   = (const float*)d_in[2];
    const float* Wf = (const float*)d_in[3];
    const float* bf_ = (const float*)d_in[4];
    const float* Wi = (const float*)d_in[5];
    const float* bi_ = (const float*)d_in[6];
    const float* Wc = (const float*)d_in[7];
    const float* bc_ = (const float*)d_in[8];
    const float* Wo = (const float*)d_in[9];
    const float* bo_ = (const float*)d_in[10];
    float* out = (float*)d_out;

    char* ws = (char*)d_ws;
    __hip_bfloat16* x  = (__hip_bfloat16*)ws;                  // 16 MB
    __hip_bfloat16* Wt = (__hip_bfloat16*)(ws + (16u << 20));  // 16 MB

    // 1) vectorized concat-cast x (4096 blocks) + W transpose-cast (2048 blocks)
    prep<<<dim3(6144), dim3(256), 0, stream>>>(hidden, inputs, Wf, Wi, Wc, Wo, x, Wt);
    // 2) barrier-free fused 4-gate GEMM + LSTM gates (512 blocks = 2/CU)
    gemm_lstm<<<dim3(512), dim3(256), 0, stream>>>(
        x, Wt, bf_, bi_, bc_, bo_, cell, out);
}